// Round 19
// baseline (135.785 us; speedup 1.0000x reference)
//
#include <hip/hip_runtime.h>
#include <math.h>

#define PI_F 3.14159265358979323846f
#define SEG 512
#define SLEN 4
typedef unsigned short u16;
typedef __attribute__((ext_vector_type(8))) short bf16x8;
typedef __attribute__((ext_vector_type(4))) float f32x4;

__device__ __forceinline__ float sigmoidf_(float x){ return __fdividef(1.0f, 1.0f+__expf(-x)); }
__device__ __forceinline__ float softplusf_(float x){
    return fmaxf(x, 0.f) + __logf(1.f + __expf(-fabsf(x)));
}
__device__ __forceinline__ float tanhpi_(float x){   // tanh(x)*PI
    float t = __expf(-2.f*fabsf(x));
    float th = __fdividef(1.f - t, 1.f + t);
    return copysignf(th, x)*PI_F;
}
__device__ __forceinline__ void fsincos(float a, float* s, float* c){
    float r = a * 0.15915494309189535f;   // a / 2pi
    r = r - floorf(r);                    // [0,1) revolutions
#if __has_builtin(__builtin_amdgcn_sinf)
    *s = __builtin_amdgcn_sinf(r);
    *c = __builtin_amdgcn_cosf(r);
#else
    float t = r * 6.283185307179586f;
    *s = __sinf(t); *c = __cosf(t);
#endif
}
__device__ __forceinline__ u16 f2bf(float f){
    unsigned u = __float_as_uint(f);
    return (u16)((u + 0x7FFFu + ((u>>16)&1u)) >> 16);
}
__device__ __forceinline__ float b2f(u16 v){
    return __uint_as_float(((unsigned)v)<<16);
}
__device__ __forceinline__ void gl_lds16(const u16* g, u16* l){
    __builtin_amdgcn_global_load_lds((const __attribute__((address_space(1))) void*)g,
                                     (__attribute__((address_space(3))) void*)l, 16, 0, 0);
}

// ---------------------------------------------------------------------------
// Fused preprocessing: [0,8192) x->bf16 cvt; [8192,9600) W transposes+cvt.
// ---------------------------------------------------------------------------
__global__ __launch_bounds__(256) void k_prep(
    const float* __restrict__ x,  u16* __restrict__ xb,
    const float* __restrict__ Wp, const float* __restrict__ Wph,
    const float* __restrict__ Wr,
    u16* __restrict__ Wt, u16* __restrict__ Wrt)
{
    __shared__ float s[32][33];
    const int bid = blockIdx.x;
    if (bid < 8192){
        size_t i = ((size_t)bid*256 + threadIdx.x)*8;
        float4 v0 = *(const float4*)&x[i];
        float4 v1 = *(const float4*)&x[i+4];
        ushort4 a = make_ushort4(f2bf(v0.x),f2bf(v0.y),f2bf(v0.z),f2bf(v0.w));
        ushort4 b = make_ushort4(f2bf(v1.x),f2bf(v1.y),f2bf(v1.z),f2bf(v1.w));
        *(ushort4*)&xb[i]   = a;
        *(ushort4*)&xb[i+4] = b;
        return;
    }
    int t = bid - 8192;
    const float* W; u16* Wo; int K, Ns, KD, bx, by;
    if (t < 768)      {           W=Wp;  Wo=Wt;            K=1024; Ns=768;  KD=1024; bx=t%24; by=t/24; }
    else if (t < 896) { int u=t-768; W=Wph; Wo=Wt+768*1024; K=1024; Ns=128;  KD=1024; bx=u%4;  by=u/4; }
    else              { int u=t-896; W=Wr;  Wo=Wrt;          K=510;  Ns=1024; KD=512;  bx=u%32; by=u/32; }
    const int tx = threadIdx.x & 31, ty = threadIdx.x >> 5;
    const int k0 = by*32, n0 = bx*32;
    #pragma unroll
    for (int i=0;i<4;i++){
        int k = k0 + ty + i*8;
        s[ty+i*8][tx] = (k < K) ? W[(size_t)k*Ns + n0 + tx] : 0.f;
    }
    __syncthreads();
    #pragma unroll
    for (int i=0;i<4;i++){
        int n = n0 + ty + i*8;
        Wo[(size_t)n*KD + k0 + tx] = f2bf(s[tx][ty+i*8]);
    }
}

// ---------------------------------------------------------------------------
// GEMM1 (R14 measured-best): C1[16384x896] bf16 = Xb @ Wt^T + bias
// 256x128 tile, 256 thr (4 waves 2x2), 3 LDS bufs (72KB -> 2 blocks/CU),
// counted vmcnt(6), chunk-XOR swizzle, 1 barrier/K-tile. Grid 448 = 8 XCD x 56.
// ---------------------------------------------------------------------------
__global__ __launch_bounds__(256,2) void k_mm1(
    const u16* __restrict__ A,     // Xb [16384][1024]
    const u16* __restrict__ Bt,    // Wt [896][1024]
    const float* __restrict__ bp, const float* __restrict__ bph,
    u16* __restrict__ C)           // [16384][896]
{
    __shared__ u16 sm[3*12288];    // 3 bufs x (A 256x32=16KB | B 128x32=8KB)
    const int bid = blockIdx.x;                 // 0..447
    const int swz = (bid & 7)*56 + (bid >> 3);  // XCD j owns 56 consecutive swz
    const int by = swz / 7, bx = swz - by*7;
    const int r0 = by*256, c0 = bx*128;
    const int tid = threadIdx.x;
    const int w = tid >> 6, lane = tid & 63;
    const int wm = w >> 1, wn = w & 1;          // 2m x 2n wave grid
    const int lr = lane & 15, lk = lane >> 4;

    const int cg = ((lane&3) ^ ((lane>>3)&3))*8;          // swizzled source chunk
    const u16* gA = A  + (size_t)(r0 + w*16 + (lane>>2))*1024 + cg;  // + j*64 rows
    const u16* gB = Bt + (size_t)(c0 + w*16 + (lane>>2))*1024 + cg;  // + j*64 rows
    const int ldsA = w*512;             // u16 offset; + j*2048
    const int ldsB = 8192 + w*512;      // u16 offset; + j*2048

    const int cs = (lk ^ ((lr>>1)&3))*8;                  // swizzled read chunk
    const int aoff = (wm*128 + lr)*32 + cs;               // + m*512
    const int boff = 8192 + (wn*64 + lr)*32 + cs;         // + n*512

    f32x4 acc[8][4] = {};

    #pragma unroll
    for (int t=0;t<2;t++){
        #pragma unroll
        for (int j=0;j<4;j++)
            gl_lds16(gA + j*64*1024 + t*32, sm + t*12288 + ldsA + j*2048);
        #pragma unroll
        for (int j=0;j<2;j++)
            gl_lds16(gB + j*64*1024 + t*32, sm + t*12288 + ldsB + j*2048);
    }
    asm volatile("s_waitcnt vmcnt(6)" ::: "memory");   // K-tile 0 resident
    __builtin_amdgcn_s_barrier();
    __builtin_amdgcn_sched_barrier(0);

    for (int k=0; k<32; ++k){
        const u16* bufp = sm + (k%3)*12288;
        u16*       bufn = sm + ((k+2)%3)*12288;
        const int  k0n  = (k+2)*32;
        bf16x8 af[8], bfr[4];

        if (k < 30){
            #pragma unroll
            for (int j=0;j<4;j++)
                gl_lds16(gA + j*64*1024 + k0n, bufn + ldsA + j*2048);
            #pragma unroll
            for (int j=0;j<2;j++)
                gl_lds16(gB + j*64*1024 + k0n, bufn + ldsB + j*2048);
        }
        af[0] = *(const bf16x8*)&bufp[aoff];
        #pragma unroll
        for (int n=0;n<4;n++) bfr[n] = *(const bf16x8*)&bufp[boff + n*512];
        #pragma unroll
        for (int m=1;m<8;m++) af[m]  = *(const bf16x8*)&bufp[aoff + m*512];

        __builtin_amdgcn_s_setprio(1);
        #pragma unroll
        for (int m=0;m<8;m++)
            #pragma unroll
            for (int n=0;n<4;n++)
                acc[m][n] = __builtin_amdgcn_mfma_f32_16x16x32_bf16(af[m], bfr[n], acc[m][n],0,0,0);
        __builtin_amdgcn_s_setprio(0);

        if (k < 30)       asm volatile("s_waitcnt vmcnt(6)" ::: "memory");
        else if (k == 30) asm volatile("s_waitcnt vmcnt(0)" ::: "memory");
        __builtin_amdgcn_s_barrier();
        __builtin_amdgcn_sched_barrier(0);
    }

    #pragma unroll
    for (int n=0;n<4;n++){
        const int col = c0 + wn*64 + n*16 + lr;
        const float bl = (col < 768) ? bp[col] : bph[col-768];
        #pragma unroll
        for (int m=0;m<8;m++){
            const int row = r0 + wm*128 + m*16 + lk*4;
            #pragma unroll
            for (int r=0;r<4;r++)
                C[(size_t)(row+r)*896 + col] = f2bf(acc[m][n][r] + bl);
        }
    }
}

// ---------------------------------------------------------------------------
// GEMM2 (R16 measured-best): O[16384x1024] = bf16(X) + rs*( F @ Wrt^T )
// 128x128 tile (3 blocks/CU), 3-buf counted-vmcnt(4) pipeline + swizzle.
// ---------------------------------------------------------------------------
__global__ __launch_bounds__(256) void k_mm2(
    const u16* __restrict__ A,     // F [16384][512]
    const u16* __restrict__ Bt,    // Wrt [1024][512]
    const u16* __restrict__ Xb,
    const float* __restrict__ rs_p,
    float* __restrict__ O)
{
    __shared__ u16 sm[3*8192];     // 3 bufs x (A 128x32=8KB | B 128x32=8KB)
    const int bid = blockIdx.x;
    const int swz = (bid & 7)*128 + (bid >> 3);
    const int by = swz >> 3, bx = swz & 7;
    const int r0 = by*128, c0 = bx*128;
    const int tid = threadIdx.x;
    const int w = tid>>6, lane = tid&63;
    const int wm = w>>1, wn = w&1;
    const int lr = lane&15, lk = lane>>4;

    const int cg = ((lane&3) ^ ((lane>>3)&3))*8;
    const u16* gA = A  + (size_t)(r0 + w*32 + (lane>>2))*512 + cg;
    const u16* gB = Bt + (size_t)(c0 + w*32 + (lane>>2))*512 + cg;
    const int ldsA = w*1024;
    const int ldsB = 4096 + w*1024;

    const int cs = (lk ^ ((lr>>1)&3))*8;
    const int aoff = (wm*64 + lr)*32 + cs;
    const int boff = 4096 + (wn*64 + lr)*32 + cs;

    f32x4 acc[4][4] = {};

    #pragma unroll
    for (int t=0;t<2;t++){
        #pragma unroll
        for (int i=0;i<2;i++){
            gl_lds16(gA + i*16*512 + t*32, sm + t*8192 + ldsA + i*512);
            gl_lds16(gB + i*16*512 + t*32, sm + t*8192 + ldsB + i*512);
        }
    }
    asm volatile("s_waitcnt vmcnt(4)" ::: "memory");
    __builtin_amdgcn_s_barrier();
    __builtin_amdgcn_sched_barrier(0);

    for (int k=0; k<16; ++k){
        const u16* bufp = sm + (k%3)*8192;
        u16*       bufn = sm + ((k+2)%3)*8192;
        const int  k0n  = (k+2)*32;
        bf16x8 af[4], bfr[4];

        if (k < 14){
            #pragma unroll
            for (int i=0;i<2;i++){
                gl_lds16(gA + i*16*512 + k0n, bufn + ldsA + i*512);
                gl_lds16(gB + i*16*512 + k0n, bufn + ldsB + i*512);
            }
        }
        af[0] = *(const bf16x8*)&bufp[aoff];
        #pragma unroll
        for (int n=0;n<4;n++) bfr[n] = *(const bf16x8*)&bufp[boff + n*512];
        #pragma unroll
        for (int m=1;m<4;m++) af[m]  = *(const bf16x8*)&bufp[aoff + m*512];

        __builtin_amdgcn_s_setprio(1);
        #pragma unroll
        for (int m=0;m<4;m++)
            #pragma unroll
            for (int n=0;n<4;n++)
                acc[m][n] = __builtin_amdgcn_mfma_f32_16x16x32_bf16(af[m], bfr[n], acc[m][n],0,0,0);
        __builtin_amdgcn_s_setprio(0);

        if (k < 14)       asm volatile("s_waitcnt vmcnt(4)" ::: "memory");
        else if (k == 14) asm volatile("s_waitcnt vmcnt(0)" ::: "memory");
        __builtin_amdgcn_s_barrier();
        __builtin_amdgcn_sched_barrier(0);
    }

    const float rs = rs_p[0];
    #pragma unroll
    for (int n=0;n<4;n++){
        int col = c0 + wn*64 + n*16 + lr;
        #pragma unroll
        for (int m=0;m<4;m++){
            int row = r0 + wm*64 + m*16 + lk*4;
            #pragma unroll
            for (int r=0;r<4;r++){
                size_t idx = (size_t)(row+r)*1024 + col;
                O[idx] = b2f(Xb[idx]) + rs*acc[m][n][r];
            }
        }
    }
}

// ---------------------------------------------------------------------------
// S1: per-segment aggregates. grid (SEG, B), block 128 (thread = k). C1 bf16.
// SLEN=4: doubles scan TLP vs SLEN=8 (trans-latency-bound chain halves).
// ---------------------------------------------------------------------------
__global__ __launch_bounds__(128) void k_s1(
    const u16* __restrict__ C1,
    const float* __restrict__ omega_base,
    float* __restrict__ Ag, float* __restrict__ Br, float* __restrict__ Bi)
{
    const int k = threadIdx.x;
    const int seg = blockIdx.x, b = blockIdx.y;
    const float ob = omega_base[k];
    const int n0 = seg*SLEN;
    float aag = 1.f, br = 0.f, bi = 0.f;
    #pragma unroll
    for (int s=0; s<SLEN; s++){
        const int n = n0 + s;
        const u16* row = C1 + (size_t)(b*2048+n)*896;
        float Ar = b2f(row[k]);
        float Om = b2f(row[128+k]);
        float Ph = b2f(row[256+k]);
        float Ga = b2f(row[384+k]);
        float alpha = sigmoidf_(Ga);
        float A = fminf(softplusf_(Ar), 3.0f);
        float omega = fminf(fmaxf(sigmoidf_(Om)*PI_F + ob, 1e-4f), PI_F-1e-4f);
        float phi = tanhpi_(Ph);
        float pos = __logf(1.f + (float)n);
        float sa, ca; fsincos(fmaf(omega, pos, phi), &sa, &ca);
        float drive = (1.f-alpha)*A;
        aag *= alpha;
        br = fmaf(alpha, br, drive*ca);
        bi = fmaf(alpha, bi, drive*sa);
    }
    const size_t o = (size_t)(b*SEG + seg)*128 + k;
    Ag[o] = aag; Br[o] = br; Bi[o] = bi;
}

// ---------------------------------------------------------------------------
// S2: serial scan over SEG aggregates per (b,k) channel; writes entry prefix.
// ---------------------------------------------------------------------------
__global__ __launch_bounds__(256) void k_s2(
    const float* __restrict__ Ag, const float* __restrict__ Br, const float* __restrict__ Bi,
    float* __restrict__ Pr, float* __restrict__ Pi)
{
    const int gid = blockIdx.x*256 + threadIdx.x;   // 0..1023
    const int b = gid >> 7, k = gid & 127;
    float pr = 0.f, pi = 0.f;
    #pragma unroll 8
    for (int seg=0; seg<SEG; seg++){
        const size_t o = (size_t)(b*SEG + seg)*128 + k;
        float a = Ag[o], r = Br[o], i = Bi[o];
        Pr[o] = pr; Pi[o] = pi;
        pr = fmaf(a, pr, r);
        pi = fmaf(a, pi, i);
    }
}

// ---------------------------------------------------------------------------
// S3: prefix replay + full post-scan elementwise + neighbor-k cross via LDS,
// writes F bf16 [16384 x 512]. C1 bf16.
// ---------------------------------------------------------------------------
__global__ __launch_bounds__(128) void k_s3(
    const u16* __restrict__ C1,
    const float* __restrict__ omega_base,
    const float* __restrict__ lam_p,
    const float* __restrict__ Pr, const float* __restrict__ Pi,
    u16* __restrict__ F)
{
    const int k = threadIdx.x;
    const int seg = blockIdx.x, b = blockIdx.y;
    const float ob = omega_base[k];
    const float lam = lam_p[0];
    __shared__ float sre[2][129], sim[2][129];

    const size_t po = (size_t)(b*SEG + seg)*128 + k;
    float rr = Pr[po], ri = Pi[po];
    const int n0 = seg*SLEN;

    #pragma unroll 2
    for (int s=0; s<SLEN; s++){
        const int n = n0 + s;
        const u16* row = C1 + (size_t)(b*2048+n)*896;
        float Ar = b2f(row[k]);
        float Om = b2f(row[128+k]);
        float Ph = b2f(row[256+k]);
        float Ga = b2f(row[384+k]);
        float Go = b2f(row[512+k]);
        float Be = b2f(row[640+k]);
        float pq = b2f(row[768+k]);
        float alpha = sigmoidf_(Ga);
        float A = fminf(softplusf_(Ar), 3.0f);
        float omega = fminf(fmaxf(sigmoidf_(Om)*PI_F + ob, 1e-4f), PI_F-1e-4f);
        float phi = tanhpi_(Ph);
        float pos = __logf(1.f + (float)n);
        float sa, ca; fsincos(fmaf(omega, pos, phi), &sa, &ca);
        float drive = (1.f-alpha)*A;
        rr = fmaf(alpha, rr, drive*ca);
        ri = fmaf(alpha, ri, drive*sa);
        float readout = rr*ca + ri*sa;
        float beta = sigmoidf_(Be);
        float r2r = rr - beta*readout*ca;
        float r2i = ri - beta*readout*sa;
        float m2 = r2r*r2r + r2i*r2i + 1e-8f;
        float inv = fminf(rsqrtf(m2), 1.0f);       // 1/max(sqrt(m2),1)
        r2r *= inv; r2i *= inv;
        float rho_re =  r2r*ca + r2i*sa;
        float rho_im = -r2r*sa + r2i*ca;
        float rho2 = rho_re*rho_re + rho_im*rho_im + 1e-6f;
        float spq, cpq; fsincos(pq, &spq, &cpq);
        float align = (rho_re*cpq + rho_im*spq)*rsqrtf(rho2);
        float gate = sigmoidf_(lam*align);
        rho_re *= gate; rho_im *= gate;
        float go = sigmoidf_(Go);

        const int buf = s & 1;
        sre[buf][k] = rho_re; sim[buf][k] = rho_im;
        __syncthreads();

        u16* frow = F + (size_t)(b*2048+n)*512;
        frow[k]       = f2bf(go*rho_re);
        frow[128 + k] = f2bf(go*rho_im);
        if (k < 127){
            float nre = sre[buf][k+1], nim = sim[buf][k+1];
            frow[256 + k] = f2bf(rho_re*nre + rho_im*nim);
            frow[383 + k] = f2bf(rho_im*nre - rho_re*nim);
        } else {
            frow[510] = 0; frow[511] = 0;
        }
    }
}

extern "C" void kernel_launch(void* const* d_in, const int* in_sizes, int n_in,
                              void* d_out, int out_size, void* d_ws, size_t ws_size,
                              hipStream_t stream)
{
    const float* x   = (const float*)d_in[0];
    const float* Wp  = (const float*)d_in[1];
    const float* bp  = (const float*)d_in[2];
    const float* ob  = (const float*)d_in[3];
    const float* Wph = (const float*)d_in[4];
    const float* bph = (const float*)d_in[5];
    const float* Wr  = (const float*)d_in[6];
    const float* lam = (const float*)d_in[7];
    const float* rs  = (const float*)d_in[8];
    float* out = (float*)d_out;

    char* ws = (char*)d_ws;
    // layout (bytes), total 93061120 (<= 95158272 used successfully in R3-R5):
    //   [0, 29360128)            C1 bf16 16384x896
    //   [29360128, +2097152)     Ag   (SEG=512: 8*512*128 fp32 = 2MB each)
    //   [31457280, +2097152)     Br
    //   [33554432, +2097152)     Bi
    //   [35651584, +2097152)     Pr
    //   [37748736, +2097152)     Pi
    //   [39845888, +16777216)    F bf16 16384x512
    //   [56623104, +1835008)     Wt bf16 896x1024
    //   [58458112, +1048576)     Wrt bf16 1024x512
    //   [59506688, +33554432)    Xb bf16 16384x1024
    u16*   C1  = (u16*)  (ws + 0);
    float* Ag  = (float*)(ws + 29360128);
    float* Brr = (float*)(ws + 31457280);
    float* Bii = (float*)(ws + 33554432);
    float* Pr  = (float*)(ws + 35651584);
    float* Pi  = (float*)(ws + 37748736);
    u16*   F   = (u16*)  (ws + 39845888);
    u16*   Wt  = (u16*)  (ws + 56623104);
    u16*   Wrt = (u16*)  (ws + 58458112);
    u16*   Xb  = (u16*)  (ws + 59506688);

    dim3 blk(256);
    hipLaunchKernelGGL(k_prep,  dim3(9600),   blk, 0, stream, x, Xb, Wp, Wph, Wr, Wt, Wrt);
    hipLaunchKernelGGL(k_mm1,   dim3(448),    blk, 0, stream, Xb, Wt, bp, bph, C1);
    hipLaunchKernelGGL(k_s1,    dim3(SEG,8),  dim3(128), 0, stream, C1, ob, Ag, Brr, Bii);
    hipLaunchKernelGGL(k_s2,    dim3(4),      blk, 0, stream, Ag, Brr, Bii, Pr, Pi);
    hipLaunchKernelGGL(k_s3,    dim3(SEG,8),  dim3(128), 0, stream, C1, ob, lam, Pr, Pi, F);
    hipLaunchKernelGGL(k_mm2,   dim3(1024),   blk, 0, stream, F, Wrt, Xb, rs, out);
}

// Round 20
// 125.016 us; speedup vs baseline: 1.0861x; 1.0861x over previous
//
#include <hip/hip_runtime.h>
#include <math.h>

#define PI_F 3.14159265358979323846f
#define SEG 256
#define SLEN 8
typedef unsigned short u16;
typedef __attribute__((ext_vector_type(8))) short bf16x8;
typedef __attribute__((ext_vector_type(4))) float f32x4;

__device__ __forceinline__ float sigmoidf_(float x){ return __fdividef(1.0f, 1.0f+__expf(-x)); }
__device__ __forceinline__ float softplusf_(float x){
    return fmaxf(x, 0.f) + __logf(1.f + __expf(-fabsf(x)));
}
__device__ __forceinline__ float tanhpi_(float x){   // tanh(x)*PI
    float t = __expf(-2.f*fabsf(x));
    float th = __fdividef(1.f - t, 1.f + t);
    return copysignf(th, x)*PI_F;
}
__device__ __forceinline__ void fsincos(float a, float* s, float* c){
    float r = a * 0.15915494309189535f;   // a / 2pi
    r = r - floorf(r);                    // [0,1) revolutions
#if __has_builtin(__builtin_amdgcn_sinf)
    *s = __builtin_amdgcn_sinf(r);
    *c = __builtin_amdgcn_cosf(r);
#else
    float t = r * 6.283185307179586f;
    *s = __sinf(t); *c = __cosf(t);
#endif
}
__device__ __forceinline__ u16 f2bf(float f){
    unsigned u = __float_as_uint(f);
    return (u16)((u + 0x7FFFu + ((u>>16)&1u)) >> 16);
}
__device__ __forceinline__ float b2f(u16 v){
    return __uint_as_float(((unsigned)v)<<16);
}
__device__ __forceinline__ void gl_lds16(const u16* g, u16* l){
    __builtin_amdgcn_global_load_lds((const __attribute__((address_space(1))) void*)g,
                                     (__attribute__((address_space(3))) void*)l, 16, 0, 0);
}

// ---------------------------------------------------------------------------
// Fused preprocessing: [0,8192) x->bf16 cvt; [8192,9600) W transposes+cvt.
// ---------------------------------------------------------------------------
__global__ __launch_bounds__(256) void k_prep(
    const float* __restrict__ x,  u16* __restrict__ xb,
    const float* __restrict__ Wp, const float* __restrict__ Wph,
    const float* __restrict__ Wr,
    u16* __restrict__ Wt, u16* __restrict__ Wrt)
{
    __shared__ float s[32][33];
    const int bid = blockIdx.x;
    if (bid < 8192){
        size_t i = ((size_t)bid*256 + threadIdx.x)*8;
        float4 v0 = *(const float4*)&x[i];
        float4 v1 = *(const float4*)&x[i+4];
        ushort4 a = make_ushort4(f2bf(v0.x),f2bf(v0.y),f2bf(v0.z),f2bf(v0.w));
        ushort4 b = make_ushort4(f2bf(v1.x),f2bf(v1.y),f2bf(v1.z),f2bf(v1.w));
        *(ushort4*)&xb[i]   = a;
        *(ushort4*)&xb[i+4] = b;
        return;
    }
    int t = bid - 8192;
    const float* W; u16* Wo; int K, Ns, KD, bx, by;
    if (t < 768)      {           W=Wp;  Wo=Wt;            K=1024; Ns=768;  KD=1024; bx=t%24; by=t/24; }
    else if (t < 896) { int u=t-768; W=Wph; Wo=Wt+768*1024; K=1024; Ns=128;  KD=1024; bx=u%4;  by=u/4; }
    else              { int u=t-896; W=Wr;  Wo=Wrt;          K=510;  Ns=1024; KD=512;  bx=u%32; by=u/32; }
    const int tx = threadIdx.x & 31, ty = threadIdx.x >> 5;
    const int k0 = by*32, n0 = bx*32;
    #pragma unroll
    for (int i=0;i<4;i++){
        int k = k0 + ty + i*8;
        s[ty+i*8][tx] = (k < K) ? W[(size_t)k*Ns + n0 + tx] : 0.f;
    }
    __syncthreads();
    #pragma unroll
    for (int i=0;i<4;i++){
        int n = n0 + ty + i*8;
        Wo[(size_t)n*KD + k0 + tx] = f2bf(s[tx][ty+i*8]);
    }
}

// ---------------------------------------------------------------------------
// GEMM1 (R14 measured-best): C1[16384x896] bf16 = Xb @ Wt^T + bias
// 256x128 tile, 256 thr (4 waves 2x2), 3 LDS bufs (72KB -> 2 blocks/CU),
// counted vmcnt(6), chunk-XOR swizzle, 1 barrier/K-tile. Grid 448 = 8 XCD x 56.
// ---------------------------------------------------------------------------
__global__ __launch_bounds__(256,2) void k_mm1(
    const u16* __restrict__ A,     // Xb [16384][1024]
    const u16* __restrict__ Bt,    // Wt [896][1024]
    const float* __restrict__ bp, const float* __restrict__ bph,
    u16* __restrict__ C)           // [16384][896]
{
    __shared__ u16 sm[3*12288];    // 3 bufs x (A 256x32=16KB | B 128x32=8KB)
    const int bid = blockIdx.x;                 // 0..447
    const int swz = (bid & 7)*56 + (bid >> 3);  // XCD j owns 56 consecutive swz
    const int by = swz / 7, bx = swz - by*7;
    const int r0 = by*256, c0 = bx*128;
    const int tid = threadIdx.x;
    const int w = tid >> 6, lane = tid & 63;
    const int wm = w >> 1, wn = w & 1;          // 2m x 2n wave grid
    const int lr = lane & 15, lk = lane >> 4;

    const int cg = ((lane&3) ^ ((lane>>3)&3))*8;          // swizzled source chunk
    const u16* gA = A  + (size_t)(r0 + w*16 + (lane>>2))*1024 + cg;  // + j*64 rows
    const u16* gB = Bt + (size_t)(c0 + w*16 + (lane>>2))*1024 + cg;  // + j*64 rows
    const int ldsA = w*512;             // u16 offset; + j*2048
    const int ldsB = 8192 + w*512;      // u16 offset; + j*2048

    const int cs = (lk ^ ((lr>>1)&3))*8;                  // swizzled read chunk
    const int aoff = (wm*128 + lr)*32 + cs;               // + m*512
    const int boff = 8192 + (wn*64 + lr)*32 + cs;         // + n*512

    f32x4 acc[8][4] = {};

    #pragma unroll
    for (int t=0;t<2;t++){
        #pragma unroll
        for (int j=0;j<4;j++)
            gl_lds16(gA + j*64*1024 + t*32, sm + t*12288 + ldsA + j*2048);
        #pragma unroll
        for (int j=0;j<2;j++)
            gl_lds16(gB + j*64*1024 + t*32, sm + t*12288 + ldsB + j*2048);
    }
    asm volatile("s_waitcnt vmcnt(6)" ::: "memory");   // K-tile 0 resident
    __builtin_amdgcn_s_barrier();
    __builtin_amdgcn_sched_barrier(0);

    for (int k=0; k<32; ++k){
        const u16* bufp = sm + (k%3)*12288;
        u16*       bufn = sm + ((k+2)%3)*12288;
        const int  k0n  = (k+2)*32;
        bf16x8 af[8], bfr[4];

        if (k < 30){
            #pragma unroll
            for (int j=0;j<4;j++)
                gl_lds16(gA + j*64*1024 + k0n, bufn + ldsA + j*2048);
            #pragma unroll
            for (int j=0;j<2;j++)
                gl_lds16(gB + j*64*1024 + k0n, bufn + ldsB + j*2048);
        }
        af[0] = *(const bf16x8*)&bufp[aoff];
        #pragma unroll
        for (int n=0;n<4;n++) bfr[n] = *(const bf16x8*)&bufp[boff + n*512];
        #pragma unroll
        for (int m=1;m<8;m++) af[m]  = *(const bf16x8*)&bufp[aoff + m*512];

        __builtin_amdgcn_s_setprio(1);
        #pragma unroll
        for (int m=0;m<8;m++)
            #pragma unroll
            for (int n=0;n<4;n++)
                acc[m][n] = __builtin_amdgcn_mfma_f32_16x16x32_bf16(af[m], bfr[n], acc[m][n],0,0,0);
        __builtin_amdgcn_s_setprio(0);

        if (k < 30)       asm volatile("s_waitcnt vmcnt(6)" ::: "memory");
        else if (k == 30) asm volatile("s_waitcnt vmcnt(0)" ::: "memory");
        __builtin_amdgcn_s_barrier();
        __builtin_amdgcn_sched_barrier(0);
    }

    #pragma unroll
    for (int n=0;n<4;n++){
        const int col = c0 + wn*64 + n*16 + lr;
        const float bl = (col < 768) ? bp[col] : bph[col-768];
        #pragma unroll
        for (int m=0;m<8;m++){
            const int row = r0 + wm*128 + m*16 + lk*4;
            #pragma unroll
            for (int r=0;r<4;r++)
                C[(size_t)(row+r)*896 + col] = f2bf(acc[m][n][r] + bl);
        }
    }
}

// ---------------------------------------------------------------------------
// GEMM2 (R16 measured-best): O[16384x1024] = bf16(X) + rs*( F @ Wrt^T )
// 128x128 tile (3 blocks/CU — occupancy is mm2's lifeline; R9/R17 lessons),
// 3-buf counted-vmcnt(4) pipeline + chunk-XOR swizzle, 1 barrier/K-tile.
// ---------------------------------------------------------------------------
__global__ __launch_bounds__(256) void k_mm2(
    const u16* __restrict__ A,     // F [16384][512]
    const u16* __restrict__ Bt,    // Wrt [1024][512]
    const u16* __restrict__ Xb,
    const float* __restrict__ rs_p,
    float* __restrict__ O)
{
    __shared__ u16 sm[3*8192];     // 3 bufs x (A 128x32=8KB | B 128x32=8KB)
    const int bid = blockIdx.x;
    const int swz = (bid & 7)*128 + (bid >> 3);
    const int by = swz >> 3, bx = swz & 7;
    const int r0 = by*128, c0 = bx*128;
    const int tid = threadIdx.x;
    const int w = tid>>6, lane = tid&63;
    const int wm = w>>1, wn = w&1;
    const int lr = lane&15, lk = lane>>4;

    const int cg = ((lane&3) ^ ((lane>>3)&3))*8;
    const u16* gA = A  + (size_t)(r0 + w*32 + (lane>>2))*512 + cg;
    const u16* gB = Bt + (size_t)(c0 + w*32 + (lane>>2))*512 + cg;
    const int ldsA = w*1024;
    const int ldsB = 4096 + w*1024;

    const int cs = (lk ^ ((lr>>1)&3))*8;
    const int aoff = (wm*64 + lr)*32 + cs;
    const int boff = 4096 + (wn*64 + lr)*32 + cs;

    f32x4 acc[4][4] = {};

    #pragma unroll
    for (int t=0;t<2;t++){
        #pragma unroll
        for (int i=0;i<2;i++){
            gl_lds16(gA + i*16*512 + t*32, sm + t*8192 + ldsA + i*512);
            gl_lds16(gB + i*16*512 + t*32, sm + t*8192 + ldsB + i*512);
        }
    }
    asm volatile("s_waitcnt vmcnt(4)" ::: "memory");
    __builtin_amdgcn_s_barrier();
    __builtin_amdgcn_sched_barrier(0);

    for (int k=0; k<16; ++k){
        const u16* bufp = sm + (k%3)*8192;
        u16*       bufn = sm + ((k+2)%3)*8192;
        const int  k0n  = (k+2)*32;
        bf16x8 af[4], bfr[4];

        if (k < 14){
            #pragma unroll
            for (int i=0;i<2;i++){
                gl_lds16(gA + i*16*512 + k0n, bufn + ldsA + i*512);
                gl_lds16(gB + i*16*512 + k0n, bufn + ldsB + i*512);
            }
        }
        af[0] = *(const bf16x8*)&bufp[aoff];
        #pragma unroll
        for (int n=0;n<4;n++) bfr[n] = *(const bf16x8*)&bufp[boff + n*512];
        #pragma unroll
        for (int m=1;m<4;m++) af[m]  = *(const bf16x8*)&bufp[aoff + m*512];

        __builtin_amdgcn_s_setprio(1);
        #pragma unroll
        for (int m=0;m<4;m++)
            #pragma unroll
            for (int n=0;n<4;n++)
                acc[m][n] = __builtin_amdgcn_mfma_f32_16x16x32_bf16(af[m], bfr[n], acc[m][n],0,0,0);
        __builtin_amdgcn_s_setprio(0);

        if (k < 14)       asm volatile("s_waitcnt vmcnt(4)" ::: "memory");
        else if (k == 14) asm volatile("s_waitcnt vmcnt(0)" ::: "memory");
        __builtin_amdgcn_s_barrier();
        __builtin_amdgcn_sched_barrier(0);
    }

    const float rs = rs_p[0];
    #pragma unroll
    for (int n=0;n<4;n++){
        int col = c0 + wn*64 + n*16 + lr;
        #pragma unroll
        for (int m=0;m<4;m++){
            int row = r0 + wm*64 + m*16 + lk*4;
            #pragma unroll
            for (int r=0;r<4;r++){
                size_t idx = (size_t)(row+r)*1024 + col;
                O[idx] = b2f(Xb[idx]) + rs*acc[m][n][r];
            }
        }
    }
}

// ---------------------------------------------------------------------------
// S1: per-segment aggregates. grid (SEG, B), block 128 (thread = k). C1 bf16.
// ---------------------------------------------------------------------------
__global__ __launch_bounds__(128) void k_s1(
    const u16* __restrict__ C1,
    const float* __restrict__ omega_base,
    float* __restrict__ Ag, float* __restrict__ Br, float* __restrict__ Bi)
{
    const int k = threadIdx.x;
    const int seg = blockIdx.x, b = blockIdx.y;
    const float ob = omega_base[k];
    const int n0 = seg*SLEN;
    float aag = 1.f, br = 0.f, bi = 0.f;
    #pragma unroll 4
    for (int s=0; s<SLEN; s++){
        const int n = n0 + s;
        const u16* row = C1 + (size_t)(b*2048+n)*896;
        float Ar = b2f(row[k]);
        float Om = b2f(row[128+k]);
        float Ph = b2f(row[256+k]);
        float Ga = b2f(row[384+k]);
        float alpha = sigmoidf_(Ga);
        float A = fminf(softplusf_(Ar), 3.0f);
        float omega = fminf(fmaxf(sigmoidf_(Om)*PI_F + ob, 1e-4f), PI_F-1e-4f);
        float phi = tanhpi_(Ph);
        float pos = __logf(1.f + (float)n);
        float sa, ca; fsincos(fmaf(omega, pos, phi), &sa, &ca);
        float drive = (1.f-alpha)*A;
        aag *= alpha;
        br = fmaf(alpha, br, drive*ca);
        bi = fmaf(alpha, bi, drive*sa);
    }
    const size_t o = (size_t)(b*SEG + seg)*128 + k;
    Ag[o] = aag; Br[o] = br; Bi[o] = bi;
}

// ---------------------------------------------------------------------------
// S2: serial scan over SEG aggregates per (b,k) channel; writes entry prefix.
// ---------------------------------------------------------------------------
__global__ __launch_bounds__(256) void k_s2(
    const float* __restrict__ Ag, const float* __restrict__ Br, const float* __restrict__ Bi,
    float* __restrict__ Pr, float* __restrict__ Pi)
{
    const int gid = blockIdx.x*256 + threadIdx.x;   // 0..1023
    const int b = gid >> 7, k = gid & 127;
    float pr = 0.f, pi = 0.f;
    #pragma unroll 8
    for (int seg=0; seg<SEG; seg++){
        const size_t o = (size_t)(b*SEG + seg)*128 + k;
        float a = Ag[o], r = Br[o], i = Bi[o];
        Pr[o] = pr; Pi[o] = pi;
        pr = fmaf(a, pr, r);
        pi = fmaf(a, pi, i);
    }
}

// ---------------------------------------------------------------------------
// S3: prefix replay + full post-scan elementwise + neighbor-k cross via LDS,
// writes F bf16 [16384 x 512]. C1 bf16.
// ---------------------------------------------------------------------------
__global__ __launch_bounds__(128) void k_s3(
    const u16* __restrict__ C1,
    const float* __restrict__ omega_base,
    const float* __restrict__ lam_p,
    const float* __restrict__ Pr, const float* __restrict__ Pi,
    u16* __restrict__ F)
{
    const int k = threadIdx.x;
    const int seg = blockIdx.x, b = blockIdx.y;
    const float ob = omega_base[k];
    const float lam = lam_p[0];
    __shared__ float sre[2][129], sim[2][129];

    const size_t po = (size_t)(b*SEG + seg)*128 + k;
    float rr = Pr[po], ri = Pi[po];
    const int n0 = seg*SLEN;

    #pragma unroll 2
    for (int s=0; s<SLEN; s++){
        const int n = n0 + s;
        const u16* row = C1 + (size_t)(b*2048+n)*896;
        float Ar = b2f(row[k]);
        float Om = b2f(row[128+k]);
        float Ph = b2f(row[256+k]);
        float Ga = b2f(row[384+k]);
        float Go = b2f(row[512+k]);
        float Be = b2f(row[640+k]);
        float pq = b2f(row[768+k]);
        float alpha = sigmoidf_(Ga);
        float A = fminf(softplusf_(Ar), 3.0f);
        float omega = fminf(fmaxf(sigmoidf_(Om)*PI_F + ob, 1e-4f), PI_F-1e-4f);
        float phi = tanhpi_(Ph);
        float pos = __logf(1.f + (float)n);
        float sa, ca; fsincos(fmaf(omega, pos, phi), &sa, &ca);
        float drive = (1.f-alpha)*A;
        rr = fmaf(alpha, rr, drive*ca);
        ri = fmaf(alpha, ri, drive*sa);
        float readout = rr*ca + ri*sa;
        float beta = sigmoidf_(Be);
        float r2r = rr - beta*readout*ca;
        float r2i = ri - beta*readout*sa;
        float m2 = r2r*r2r + r2i*r2i + 1e-8f;
        float inv = fminf(rsqrtf(m2), 1.0f);       // 1/max(sqrt(m2),1)
        r2r *= inv; r2i *= inv;
        float rho_re =  r2r*ca + r2i*sa;
        float rho_im = -r2r*sa + r2i*ca;
        float rho2 = rho_re*rho_re + rho_im*rho_im + 1e-6f;
        float spq, cpq; fsincos(pq, &spq, &cpq);
        float align = (rho_re*cpq + rho_im*spq)*rsqrtf(rho2);
        float gate = sigmoidf_(lam*align);
        rho_re *= gate; rho_im *= gate;
        float go = sigmoidf_(Go);

        const int buf = s & 1;
        sre[buf][k] = rho_re; sim[buf][k] = rho_im;
        __syncthreads();

        u16* frow = F + (size_t)(b*2048+n)*512;
        frow[k]       = f2bf(go*rho_re);
        frow[128 + k] = f2bf(go*rho_im);
        if (k < 127){
            float nre = sre[buf][k+1], nim = sim[buf][k+1];
            frow[256 + k] = f2bf(rho_re*nre + rho_im*nim);
            frow[383 + k] = f2bf(rho_im*nre - rho_re*nim);
        } else {
            frow[510] = 0; frow[511] = 0;
        }
    }
}

extern "C" void kernel_launch(void* const* d_in, const int* in_sizes, int n_in,
                              void* d_out, int out_size, void* d_ws, size_t ws_size,
                              hipStream_t stream)
{
    const float* x   = (const float*)d_in[0];
    const float* Wp  = (const float*)d_in[1];
    const float* bp  = (const float*)d_in[2];
    const float* ob  = (const float*)d_in[3];
    const float* Wph = (const float*)d_in[4];
    const float* bph = (const float*)d_in[5];
    const float* Wr  = (const float*)d_in[6];
    const float* lam = (const float*)d_in[7];
    const float* rs  = (const float*)d_in[8];
    float* out = (float*)d_out;

    char* ws = (char*)d_ws;
    // layout (bytes), max 92274688:
    //   [0, 29360128)            C1 bf16 16384x896
    //   [29360128, +1048576)     Ag   (SEG=256: 8*256*128 fp32 = 1MB each)
    //   [30408704, +1048576)     Br
    //   [31457280, +1048576)     Bi
    //   [32505856, +1048576)     Pr
    //   [33554432, +1048576)     Pi
    //   [34603008, +16777216)    F bf16 16384x512
    //   [51380224, +1835008)     Wt bf16 896x1024
    //   [53215232, +1048576)     Wrt bf16 1024x512
    //   [58720256, +33554432)    Xb bf16 16384x1024
    u16*   C1  = (u16*)  (ws + 0);
    float* Ag  = (float*)(ws + 29360128);
    float* Brr = (float*)(ws + 30408704);
    float* Bii = (float*)(ws + 31457280);
    float* Pr  = (float*)(ws + 32505856);
    float* Pi  = (float*)(ws + 33554432);
    u16*   F   = (u16*)  (ws + 34603008);
    u16*   Wt  = (u16*)  (ws + 51380224);
    u16*   Wrt = (u16*)  (ws + 53215232);
    u16*   Xb  = (u16*)  (ws + 58720256);

    dim3 blk(256);
    hipLaunchKernelGGL(k_prep,  dim3(9600),   blk, 0, stream, x, Xb, Wp, Wph, Wr, Wt, Wrt);
    hipLaunchKernelGGL(k_mm1,   dim3(448),    blk, 0, stream, Xb, Wt, bp, bph, C1);
    hipLaunchKernelGGL(k_s1,    dim3(SEG,8),  dim3(128), 0, stream, C1, ob, Ag, Brr, Bii);
    hipLaunchKernelGGL(k_s2,    dim3(4),      blk, 0, stream, Ag, Brr, Bii, Pr, Pi);
    hipLaunchKernelGGL(k_s3,    dim3(SEG,8),  dim3(128), 0, stream, C1, ob, lam, Pr, Pi, F);
    hipLaunchKernelGGL(k_mm2,   dim3(1024),   blk, 0, stream, F, Wrt, Xb, rs, out);
}